// Round 5
// baseline (383.669 us; speedup 1.0000x reference)
//
#include <hip/hip_runtime.h>
#include <hip/hip_bf16.h>
#include <stdint.h>

#define SEQ 4096
#define BATCH 16
#define HID 512
#define ATT_OFF (BATCH * HID)                 // 8192  elements into d_out
#define NSS_OFF (BATCH * HID + BATCH * SEQ)   // 73728 elements into d_out
#define NCH 512                               // ctx chunks (8 s each)

typedef unsigned short u16;
typedef unsigned int u32;

__device__ __forceinline__ float bflo(u32 w) { return __uint_as_float(w << 16); }
__device__ __forceinline__ float bfhi(u32 w) { return __uint_as_float(w & 0xffff0000u); }

__device__ __forceinline__ u16 f2bf(float f) {  // round-to-nearest-even
  u32 u = __float_as_uint(f);
  return (u16)((u + 0x7fffu + ((u >> 16) & 1u)) >> 16);
}

// Runtime dtype probe (insurance; R1-NaN vs R2-pass proved fp32).
__device__ __forceinline__ int probe_bf16(const void* tssp) {
  const u16* t = (const u16*)tssp;
  int ok = 1;
  #pragma unroll
  for (int i = 0; i < 8; i += 2) {
    u16 u = t[i];
    ok &= (u >= 0x3F00 && u <= 0x3FC0) ? 1 : 0;
  }
  return ok;
}

template <int BF>
__device__ __forceinline__ float ld1(const void* p, size_t i) {
  if (BF) return __uint_as_float(((u32)((const u16*)p)[i]) << 16);
  return ((const float*)p)[i];
}

template <int BF>
__device__ __forceinline__ void st1(void* p, size_t i, float v) {
  if (BF) ((u16*)p)[i] = f2bf(v);
  else    ((float*)p)[i] = v;
}

template <int BF>
__device__ __forceinline__ void load8(const void* p, size_t e, float* o) {
  if (BF) {
    uint4 v = *(const uint4*)((const u16*)p + e);
    o[0]=bflo(v.x); o[1]=bfhi(v.x); o[2]=bflo(v.y); o[3]=bfhi(v.y);
    o[4]=bflo(v.z); o[5]=bfhi(v.z); o[6]=bflo(v.w); o[7]=bfhi(v.w);
  } else {
    const float4* f = (const float4*)((const float*)p + e);
    float4 a = f[0], b = f[1];
    o[0]=a.x; o[1]=a.y; o[2]=a.z; o[3]=a.w;
    o[4]=b.x; o[5]=b.y; o[6]=b.z; o[7]=b.w;
  }
}

__device__ __forceinline__ float fast_tanh(float x) {
  float e = __expf(2.0f * x);
  return 1.0f - 2.0f * __builtin_amdgcn_rcpf(e + 1.0f);
}

// ---------- K0: streaming-BW probe (m13 pattern) over ef ----------
// Pure grid-stride float4 read + checksum. Measures this harness-state's
// achievable read BW for this very buffer. Dtype-aware byte count.
__global__ __launch_bounds__(256) void k_probe(
    const void* efv, const void* tssp, float* __restrict__ pout) {
  const float4* ef = (const float4*)efv;
  size_t g = (size_t)blockIdx.x * 256 + threadIdx.x;
  int iters = probe_bf16(tssp) ? 8 : 16;   // bf16 buffer is half the bytes
  float acc = 0.0f;
  for (int i = 0; i < iters; ++i) {
    float4 v = ef[g + (size_t)i * 524288];
    acc += v.x + v.y + v.z + v.w;
  }
  pout[g] = acc;
}

// ---------- K1: dec[b,k] = sum_h oh[b,h]*W[k,h] + bias[k] ----------
template <int BF>
__device__ __forceinline__ void k_dec_body(
    const void* oh, const void* W, const void* bias, float* dec) {
  int tid = threadIdx.x;
  int gw = blockIdx.x * 4 + (tid >> 6);   // 8192 waves = 16 b * 512 k
  int lane = tid & 63;
  int k = gw & (HID - 1);
  int b = gw >> 9;
  float wv[8], ov[8];
  load8<BF>(W,  (size_t)k * HID + lane * 8, wv);
  load8<BF>(oh, (size_t)b * HID + lane * 8, ov);
  float acc = 0.0f;
  #pragma unroll
  for (int j = 0; j < 8; ++j) acc += wv[j] * ov[j];
  #pragma unroll
  for (int off = 32; off; off >>= 1) acc += __shfl_xor(acc, off, 64);
  if (lane == 0) dec[b * HID + k] = acc + ld1<BF>(bias, k);
}

__global__ __launch_bounds__(256) void k_dec(
    const void* oh, const void* W, const void* bias, const void* tss,
    float* dec) {
  if (probe_bf16(tss)) k_dec_body<1>(oh, W, bias, dec);
  else                 k_dec_body<0>(oh, W, bias, dec);
}

// ---------- K2: scores, CONTIGUOUS geometry ----------
// 512 blocks, each owns 8 consecutive s x ALL 16 b = 256 KB linear of ef.
// Wave owns 2 s; processes 4 groups of 8 consecutive rows (fixed s, b-octet):
// each group = 16 KB contiguous. dec tile (32 KB) preloaded to LDS.
template <int BF>
__device__ __forceinline__ void k_scores_body(
    const void* ef, const void* maskp, const void* tssp, const void* vp,
    const float* dec, float* w_buf, void* out) {
  int tid = threadIdx.x, lane = tid & 63, wave = tid >> 6;
  int s0 = blockIdx.x * 8;
  __shared__ float dlds[BATCH * HID];
  {
    const float4* src = (const float4*)dec;
    float4* dst = (float4*)dlds;
    #pragma unroll
    for (int i = 0; i < 8; ++i) dst[tid * 8 + i] = src[tid * 8 + i];
  }
  float vv[8];
  load8<BF>(vp, lane * 8, vv);
  __syncthreads();
  #pragma unroll
  for (int g = 0; g < 4; ++g) {
    int s  = s0 + wave * 2 + (g >> 1);
    int b0 = (g & 1) * 8;
    float acc[8];
    #pragma unroll
    for (int i = 0; i < 8; ++i) {
      float ev[8];
      load8<BF>(ef, ((size_t)s * BATCH + b0 + i) * HID + lane * 8, ev);
      const float4* dv4 = (const float4*)&dlds[(b0 + i) * HID + lane * 8];
      float4 dA = dv4[0], dB = dv4[1];
      float dv[8] = {dA.x, dA.y, dA.z, dA.w, dB.x, dB.y, dB.z, dB.w};
      float a = 0.0f;
      #pragma unroll
      for (int j = 0; j < 8; ++j) a += fast_tanh(ev[j] + dv[j]) * vv[j];
      acc[i] = a;
    }
    #pragma unroll
    for (int off = 32; off; off >>= 1)
      #pragma unroll
      for (int i = 0; i < 8; ++i) acc[i] += __shfl_xor(acc[i], off, 64);
    #pragma unroll
    for (int i = 0; i < 8; ++i) {
      int b = b0 + i;
      float p  = __expf(acc[i]);
      float ts = ld1<BF>(tssp,  (size_t)b * SEQ + s);
      float m  = ld1<BF>(maskp, (size_t)b * SEQ + s);
      float w  = p * m * __builtin_amdgcn_rcpf(ts);
      if (lane == 0) {
        st1<BF>(out, NSS_OFF + (size_t)b * SEQ + s, p + ts);
        w_buf[(size_t)b * SEQ + s] = w;
      }
    }
  }
}

__global__ __launch_bounds__(256) void k_scores(
    const void* ef, const void* maskp, const void* tssp, const void* vp,
    const float* dec, float* w_buf, void* out) {
  if (probe_bf16(tssp)) k_scores_body<1>(ef, maskp, tssp, vp, dec, w_buf, out);
  else                  k_scores_body<0>(ef, maskp, tssp, vp, dec, w_buf, out);
}

// ---------- K3: context, CONTIGUOUS geometry ----------
// 512 blocks, each owns 8 consecutive s x ALL 16 b = 256 KB linear of eo.
// Lane<->h mapping h = lane + 64k (dword loads, 256 B/instr coalesced) so the
// LDS tile accumulation hits bank = lane mod 32 -> 2-way alias = free.
// Per-block 32 KB fp32 tile -> partial[b][chunk][h].
template <int BF>
__device__ __forceinline__ void k_ctx_body(
    const void* eo, const float* w_buf, float* partial) {
  int tid = threadIdx.x, lane = tid & 63, wave = tid >> 6;
  int blk = blockIdx.x;
  int s0 = blk * 8;
  __shared__ float tile[BATCH * HID];
  {
    float4* t4 = (float4*)tile;
    #pragma unroll
    for (int i = 0; i < 8; ++i) t4[tid * 8 + i] = make_float4(0, 0, 0, 0);
  }
  __syncthreads();
  int sA = s0 + wave * 2, sB = sA + 1;
  #pragma unroll 2
  for (int b = 0; b < BATCH; ++b) {
    float wA = w_buf[(size_t)b * SEQ + sA];
    float wB = w_buf[(size_t)b * SEQ + sB];
    size_t rA = ((size_t)sA * BATCH + b) * HID;
    size_t rB = ((size_t)sB * BATCH + b) * HID;
    float a[8];
    #pragma unroll
    for (int k = 0; k < 8; ++k) {
      float eA = ld1<BF>(eo, rA + lane + 64 * k);
      float eB = ld1<BF>(eo, rB + lane + 64 * k);
      a[k] = wA * eA + wB * eB;
    }
    #pragma unroll
    for (int k = 0; k < 8; ++k)
      atomicAdd(&tile[b * HID + lane + 64 * k], a[k]);
  }
  __syncthreads();
  #pragma unroll
  for (int q = 0; q < 8; ++q) {
    int fidx = (tid * 8 + q) * 4;
    int b = fidx >> 9, h = fidx & 511;
    *(float4*)(partial + ((size_t)b * NCH + blk) * HID + h) = *(float4*)(tile + fidx);
  }
}

__global__ __launch_bounds__(256) void k_ctx(
    const void* eo, const float* w_buf, const void* tssp, float* partial) {
  if (probe_bf16(tssp)) k_ctx_body<1>(eo, w_buf, partial);
  else                  k_ctx_body<0>(eo, w_buf, partial);
}

// ---------- K4: denom + att (16 blocks, one per b) ----------
template <int BF>
__device__ __forceinline__ void fin_att_body(
    const float* w_buf, float* denom_ws, void* out) {
  int b = blockIdx.x, t = threadIdx.x;
  float wl[16];
  float ps = 0.0f;
  #pragma unroll
  for (int k = 0; k < 16; ++k) {
    wl[k] = w_buf[(size_t)b * SEQ + k * 256 + t];
    ps += wl[k];
  }
  #pragma unroll
  for (int off = 32; off; off >>= 1) ps += __shfl_xor(ps, off, 64);
  __shared__ float r[4];
  if ((t & 63) == 0) r[t >> 6] = ps;
  __syncthreads();
  float denom = r[0] + r[1] + r[2] + r[3];
  float inv = __builtin_amdgcn_rcpf(denom);
  if (t == 0) denom_ws[b] = denom;
  #pragma unroll
  for (int k = 0; k < 16; ++k)
    st1<BF>(out, ATT_OFF + (size_t)b * SEQ + k * 256 + t, wl[k] * inv);
}

__global__ __launch_bounds__(256) void k_fin_att(
    const float* w_buf, float* denom_ws, const void* tssp, void* out) {
  if (probe_bf16(tssp)) fin_att_body<1>(w_buf, denom_ws, out);
  else                  fin_att_body<0>(w_buf, denom_ws, out);
}

// ---------- K5: ctx reduce (32 blocks = 16 b x 2 h-halves) ----------
template <int BF>
__device__ __forceinline__ void fin_ctx_body(
    const float* partial, const float* denom_ws, void* out) {
  int b = blockIdx.x >> 1;
  int h = ((blockIdx.x & 1) << 8) + threadIdx.x;
  const float* base = partial + (size_t)b * NCH * HID + h;
  float a0 = 0, a1 = 0, a2 = 0, a3 = 0;
  for (int c = 0; c < NCH; c += 4) {
    a0 += base[(size_t)c * HID];
    a1 += base[(size_t)(c + 1) * HID];
    a2 += base[(size_t)(c + 2) * HID];
    a3 += base[(size_t)(c + 3) * HID];
  }
  st1<BF>(out, (size_t)b * HID + h,
          (a0 + a1 + a2 + a3) * __builtin_amdgcn_rcpf(denom_ws[b]));
}

__global__ __launch_bounds__(256) void k_fin_ctx(
    const float* partial, const float* denom_ws, const void* tssp, void* out) {
  if (probe_bf16(tssp)) fin_ctx_body<1>(partial, denom_ws, out);
  else                  fin_ctx_body<0>(partial, denom_ws, out);
}

extern "C" void kernel_launch(void* const* d_in, const int* in_sizes, int n_in,
                              void* d_out, int out_size, void* d_ws, size_t ws_size,
                              hipStream_t stream) {
  const void* oh   = d_in[0];
  const void* eo   = d_in[1];
  const void* ef   = d_in[2];
  const void* mask = d_in[3];
  const void* tss  = d_in[4];
  const void* W    = d_in[5];
  const void* bias = d_in[6];
  const void* v    = d_in[7];

  float* ws       = (float*)d_ws;
  float* dec      = ws;                         // 8192
  float* w_buf    = dec + BATCH * HID;          // 65536
  float* denom_ws = w_buf + BATCH * SEQ;        // 16
  float* partial  = denom_ws + 16;              // 16*512*512 = 4194304
  float* probe_o  = partial + BATCH * NCH * HID;// 524288  (~19 MB total)

  k_probe  <<<2048, 256, 0, stream>>>(ef, tss, probe_o);
  k_dec    <<<2048, 256, 0, stream>>>(oh, W, bias, tss, dec);
  k_scores <<< 512, 256, 0, stream>>>(ef, mask, tss, v, dec, w_buf, d_out);
  k_ctx    <<< 512, 256, 0, stream>>>(eo, w_buf, tss, partial);
  k_fin_att<<<  16, 256, 0, stream>>>(w_buf, denom_ws, tss, d_out);
  k_fin_ctx<<<  32, 256, 0, stream>>>(partial, denom_ws, tss, d_out);
}